// Round 5
// baseline (234.403 us; speedup 1.0000x reference)
//
#include <hip/hip_runtime.h>

typedef __attribute__((ext_vector_type(4))) float  f32x4;
typedef __attribute__((ext_vector_type(8))) __bf16 bf16x8;

// Chaining permutation (r3-verified). D-pos q = mf*16+g4*4+r, B-pos p = kk*32+g4*8+j.
// B_next[kk][j] = relu(acc[(kk<<1)|(j>>2)][j&3]) iff weight COLUMNS are permuted by
// P(q) = (q>>5)*32 + ((q>>2)&3)*8 + ((q>>4)&1)*4 + (q&3)  (= Q^{-1}).
__device__ __forceinline__ int Pq(int q) {
  return ((q >> 5) << 5) + (((q >> 2) & 3) << 3) + (((q >> 4) & 1) << 2) + (q & 3);
}

// ---------------- setup: weights -> A-fragment order, columns permuted by P ----------
__global__ void reformat_w(const float* __restrict__ h_wh,
                           const float* __restrict__ g_w1,
                           const float* __restrict__ g_wh,
                           __bf16* __restrict__ wsH,   // [2*64][4096]
                           __bf16* __restrict__ wsG)   // [3][4096]
{
  int i = blockIdx.x * 256 + threadIdx.x;
  int j = i & 7, lane = (i >> 3) & 63, f = (i >> 9) & 7;
  int c = lane & 15, g4 = lane >> 4, mf = f >> 1, kk = f & 1;
  int krow = (kk << 5) + (g4 << 3) + j;
  int mcol = Pq((mf << 4) + c);
  if (i < 524288) {                       // h: 2 layers * 64 heads * 4096
    int ld = i >> 12;
    wsH[i] = (__bf16)h_wh[(ld << 12) + (krow << 6) + mcol];
  } else if (i < 536576) {                // g: 3 matrices * 4096
    int t = i - 524288;
    int lg = t >> 12;
    const float* W = (lg == 0) ? g_w1 : g_wh + ((lg - 1) << 12);
    wsG[t] = (__bf16)W[(krow << 6) + mcol];
  }
}

// One MFMA layer: acc = A*B + bias; optionally rebuild B-frags from acc (relu+cvt,
// pure register renaming thanks to the P-permuted weights).
__device__ __forceinline__ void layer(const __bf16* __restrict__ wf,
                                      const float* __restrict__ bias,
                                      int lane, int g4, bool rebuild,
                                      f32x4 (&acc)[4][4], bf16x8 (&bfr)[4][2])
{
  bf16x8 aw0[4], aw1[4];
  #pragma unroll
  for (int mf = 0; mf < 4; ++mf) {
    aw0[mf] = *(const bf16x8*)&wf[((mf << 1) << 9) + (lane << 3)];
    aw1[mf] = *(const bf16x8*)&wf[(((mf << 1) | 1) << 9) + (lane << 3)];
  }
  f32x4 bv[4];
  #pragma unroll
  for (int mf = 0; mf < 4; ++mf)   // bias at D-pos q: bias[P(q)], contiguous x4
    bv[mf] = *(const f32x4*)&bias[((mf >> 1) << 5) + (g4 << 3) + ((mf & 1) << 2)];
  #pragma unroll
  for (int mf = 0; mf < 4; ++mf)
    #pragma unroll
    for (int nf = 0; nf < 4; ++nf)
      acc[mf][nf] = __builtin_amdgcn_mfma_f32_16x16x32_bf16(aw0[mf], bfr[nf][0], bv[mf], 0, 0, 0);
  #pragma unroll
  for (int mf = 0; mf < 4; ++mf)
    #pragma unroll
    for (int nf = 0; nf < 4; ++nf)
      acc[mf][nf] = __builtin_amdgcn_mfma_f32_16x16x32_bf16(aw1[mf], bfr[nf][1], acc[mf][nf], 0, 0, 0);
  if (rebuild) {
    #pragma unroll
    for (int nf = 0; nf < 4; ++nf)
      #pragma unroll
      for (int kk = 0; kk < 2; ++kk) {
        bf16x8 v;
        #pragma unroll
        for (int e = 0; e < 8; ++e)
          v[e] = (__bf16)fmaxf(acc[(kk << 1) | (e >> 2)][nf][e & 3], 0.f);
        bfr[nf][kk] = v;
      }
  }
}

// Block = 512 threads / 8 waves.
// h-blocks: cover 128 batches x 16 consecutive d.  wave wid: bh=wid>>2 (batch half),
//   wq=wid&3 (d quad); wave computes d = d0+wq*4+{0..3} for batches nb..nb+63.
//   Epilogue: lane holds batch nb+lane's result for 4 CONSECUTIVE d -> one 16B store;
//   4 wq-waves tile each 64B output line fully (d0 is 16-aligned).
// g-blocks: 8 waves x 64 batches, 3 layers, coalesced 4B/lane store.
__global__ __launch_bounds__(512, 4) void fused_nn(
    const float* __restrict__ x,
    const float* __restrict__ h_w1, const float* __restrict__ h_b1,
    const float* __restrict__ h_bh,
    const float* __restrict__ h_wo, const float* __restrict__ h_bo,
    const float* __restrict__ g_b1, const float* __restrict__ g_bh,
    const float* __restrict__ g_wo, const float* __restrict__ g_bo,
    const __bf16* __restrict__ wsH, const __bf16* __restrict__ wsG,
    float* __restrict__ out, int Btot, int nwg, int nh)
{
  const int tid  = threadIdx.x;
  const int lane = tid & 63;
  const int wid  = tid >> 6;
  const int c    = lane & 15;
  const int g4   = lane >> 4;

  // XCD-bijective swizzle (nwg % 8 == 0): each XCD gets a contiguous bid range.
  const int b0  = blockIdx.x;
  const int bid = (b0 & 7) * (nwg >> 3) + (b0 >> 3);

  if (bid < nh) {
    // ---------------- h branch ----------------
    const int tile = bid >> 2;
    const int d0   = (bid & 3) << 4;
    const int bh   = wid >> 2;
    const int wq   = wid & 3;
    const int nb   = (tile << 7) + (bh << 6);

    f32x4 outv;
    #pragma unroll
    for (int dl = 0; dl < 4; ++dl) {
      const int d = d0 + (wq << 2) + dl;
      f32x4  acc[4][4];
      bf16x8 bfr[4][2];

      // h1 = relu(s * w1 + b1), built directly as B-fragments
      const float* w1p = h_w1 + (d << 6);
      const float* b1p = h_b1 + (d << 6);
      f32x4 w1v[2][2], b1v[2][2];
      #pragma unroll
      for (int kk = 0; kk < 2; ++kk)
        #pragma unroll
        for (int h = 0; h < 2; ++h) {
          int off = (kk << 5) + (g4 << 3) + (h << 2);
          w1v[kk][h] = *(const f32x4*)&w1p[off];
          b1v[kk][h] = *(const f32x4*)&b1p[off];
        }
      #pragma unroll
      for (int nf = 0; nf < 4; ++nf) {
        float s = x[(size_t)(nb + (nf << 4) + c) * 128 + 64 + d];
        #pragma unroll
        for (int kk = 0; kk < 2; ++kk) {
          bf16x8 v;
          #pragma unroll
          for (int h = 0; h < 2; ++h)
            #pragma unroll
            for (int r = 0; r < 4; ++r)
              v[(h << 2) + r] = (__bf16)fmaxf(fmaf(s, w1v[kk][h][r], b1v[kk][h][r]), 0.f);
          bfr[nf][kk] = v;
        }
      }

      layer(wsH + (d << 12),        h_bh + (d << 6),        lane, g4, true,  acc, bfr);
      layer(wsH + ((64 + d) << 12), h_bh + ((64 + d) << 6), lane, g4, false, acc, bfr);

      // epilogue: relu -> dot(wo[P(q)]) -> reduce over g4 groups
      const float* wo = h_wo + (d << 6);
      f32x4 wv[4];
      #pragma unroll
      for (int mf = 0; mf < 4; ++mf)
        wv[mf] = *(const f32x4*)&wo[((mf >> 1) << 5) + (g4 << 3) + ((mf & 1) << 2)];
      float p[4] = {0.f, 0.f, 0.f, 0.f};
      #pragma unroll
      for (int mf = 0; mf < 4; ++mf)
        #pragma unroll
        for (int nf = 0; nf < 4; ++nf)
          #pragma unroll
          for (int r = 0; r < 4; ++r)
            p[nf] += fmaxf(acc[mf][nf][r], 0.f) * wv[mf][r];
      #pragma unroll
      for (int nf = 0; nf < 4; ++nf) {
        p[nf] += __shfl_xor(p[nf], 16);
        p[nf] += __shfl_xor(p[nf], 32);
      }
      float sel = (g4 == 0) ? p[0] : (g4 == 1) ? p[1] : (g4 == 2) ? p[2] : p[3];
      outv[dl] = sel + h_bo[d];
    }
    // one full 16B store per lane; block covers the full 64B line per batch
    *(f32x4*)&out[(size_t)(nb + lane) * 64 + d0 + (wq << 2)] = outv;

  } else {
    // ---------------- g branch ----------------
    const int gt = bid - nh;
    const int nb = (gt << 9) + (wid << 6);

    f32x4  acc[4][4];
    bf16x8 bfr[4][2];
    #pragma unroll
    for (int nf = 0; nf < 4; ++nf) {
      const float* xr = x + (size_t)(nb + (nf << 4) + c) * 128;
      #pragma unroll
      for (int kk = 0; kk < 2; ++kk) {
        f32x4 v0 = *(const f32x4*)&xr[(kk << 5) + (g4 << 3)];
        f32x4 v1 = *(const f32x4*)&xr[(kk << 5) + (g4 << 3) + 4];
        bf16x8 v;
        #pragma unroll
        for (int r = 0; r < 4; ++r) { v[r] = (__bf16)v0[r]; v[4 + r] = (__bf16)v1[r]; }
        bfr[nf][kk] = v;
      }
    }
    layer(wsG,        g_b1,      lane, g4, true,  acc, bfr);
    layer(wsG + 4096, g_bh,      lane, g4, true,  acc, bfr);
    layer(wsG + 8192, g_bh + 64, lane, g4, false, acc, bfr);

    const float* wo = g_wo;
    f32x4 wv[4];
    #pragma unroll
    for (int mf = 0; mf < 4; ++mf)
      wv[mf] = *(const f32x4*)&wo[((mf >> 1) << 5) + (g4 << 3) + ((mf & 1) << 2)];
    float p[4] = {0.f, 0.f, 0.f, 0.f};
    #pragma unroll
    for (int mf = 0; mf < 4; ++mf)
      #pragma unroll
      for (int nf = 0; nf < 4; ++nf)
        #pragma unroll
        for (int r = 0; r < 4; ++r)
          p[nf] += fmaxf(acc[mf][nf][r], 0.f) * wv[mf][r];
    #pragma unroll
    for (int nf = 0; nf < 4; ++nf) {
      p[nf] += __shfl_xor(p[nf], 16);
      p[nf] += __shfl_xor(p[nf], 32);
    }
    float sel = (g4 == 0) ? p[0] : (g4 == 1) ? p[1] : (g4 == 2) ? p[2] : p[3];
    out[((size_t)Btot << 6) + nb + lane] = sel + g_bo[0];
  }
}

extern "C" void kernel_launch(void* const* d_in, const int* in_sizes, int n_in,
                              void* d_out, int out_size, void* d_ws, size_t ws_size,
                              hipStream_t stream) {
  const float* x    = (const float*)d_in[0];
  const float* h_w1 = (const float*)d_in[1];
  const float* h_b1 = (const float*)d_in[2];
  const float* h_wh = (const float*)d_in[3];
  const float* h_bh = (const float*)d_in[4];
  const float* h_wo = (const float*)d_in[5];
  const float* h_bo = (const float*)d_in[6];
  const float* g_w1 = (const float*)d_in[7];
  const float* g_b1 = (const float*)d_in[8];
  const float* g_wh = (const float*)d_in[9];
  const float* g_bh = (const float*)d_in[10];
  const float* g_wo = (const float*)d_in[11];
  const float* g_bo = (const float*)d_in[12];

  __bf16* wsH = (__bf16*)d_ws;                               // 1 MB
  __bf16* wsG = (__bf16*)((char*)d_ws + 2 * 64 * 4096 * 2);  // 24 KB

  const int Btot = in_sizes[0] / 128;     // 32768
  const int nh   = (Btot >> 7) << 2;      // 1024 h-blocks (128 batches x 16 d each)
  const int ng   = Btot >> 9;             // 64 g-blocks (512 batches each)
  const int nwg  = nh + ng;               // 1088, % 8 == 0

  hipLaunchKernelGGL(reformat_w, dim3(2096), dim3(256), 0, stream,
                     h_wh, g_w1, g_wh, wsH, wsG);

  hipLaunchKernelGGL(fused_nn, dim3(nwg), dim3(512), 0, stream,
                     x, h_w1, h_b1, h_bh, h_wo, h_bo,
                     g_b1, g_bh, g_wo, g_bo,
                     (const __bf16*)wsH, (const __bf16*)wsG,
                     (float*)d_out, Btot, nwg, nh);
}

// Round 6
// 106.258 us; speedup vs baseline: 2.2060x; 2.2060x over previous
//
#include <hip/hip_runtime.h>

typedef __attribute__((ext_vector_type(4))) float  f32x4;
typedef __attribute__((ext_vector_type(8))) __bf16 bf16x8;

// Chaining permutation (r3-verified). D-pos q = mf*16+g4*4+r, B-pos p = kk*32+g4*8+j.
// B_next[kk][j] = relu(acc[(kk<<1)|(j>>2)][j&3]) iff weight COLUMNS are permuted by
// P(q) = (q>>5)*32 + ((q>>2)&3)*8 + ((q>>4)&1)*4 + (q&3)  (= Q^{-1}).
__device__ __forceinline__ int Pq(int q) {
  return ((q >> 5) << 5) + (((q >> 2) & 3) << 3) + (((q >> 4) & 1) << 2) + (q & 3);
}

// ---------------- setup: weights -> A-fragment order, columns permuted by P ----------
__global__ void reformat_w(const float* __restrict__ h_wh,
                           const float* __restrict__ g_w1,
                           const float* __restrict__ g_wh,
                           __bf16* __restrict__ wsH,   // [2*64][4096]
                           __bf16* __restrict__ wsG)   // [3][4096]
{
  int i = blockIdx.x * 256 + threadIdx.x;
  int j = i & 7, lane = (i >> 3) & 63, f = (i >> 9) & 7;
  int c = lane & 15, g4 = lane >> 4, mf = f >> 1, kk = f & 1;
  int krow = (kk << 5) + (g4 << 3) + j;
  int mcol = Pq((mf << 4) + c);
  if (i < 524288) {                       // h: 2 layers * 64 heads * 4096
    int ld = i >> 12;
    wsH[i] = (__bf16)h_wh[(ld << 12) + (krow << 6) + mcol];
  } else if (i < 536576) {                // g: 3 matrices * 4096
    int t = i - 524288;
    int lg = t >> 12;
    const float* W = (lg == 0) ? g_w1 : g_wh + ((lg - 1) << 12);
    wsG[t] = (__bf16)W[(krow << 6) + mcol];
  }
}

// One MFMA layer: acc = A*B + bias; optionally rebuild B-frags from acc (relu+cvt,
// pure register renaming thanks to the P-permuted weights).
__device__ __forceinline__ void layer(const __bf16* __restrict__ wf,
                                      const float* __restrict__ bias,
                                      int lane, int g4, bool rebuild,
                                      f32x4 (&acc)[4][4], bf16x8 (&bfr)[4][2])
{
  bf16x8 aw0[4], aw1[4];
  #pragma unroll
  for (int mf = 0; mf < 4; ++mf) {
    aw0[mf] = *(const bf16x8*)&wf[((mf << 1) << 9) + (lane << 3)];
    aw1[mf] = *(const bf16x8*)&wf[(((mf << 1) | 1) << 9) + (lane << 3)];
  }
  f32x4 bv[4];
  #pragma unroll
  for (int mf = 0; mf < 4; ++mf)   // bias at D-pos q: bias[P(q)], contiguous x4
    bv[mf] = *(const f32x4*)&bias[((mf >> 1) << 5) + (g4 << 3) + ((mf & 1) << 2)];
  #pragma unroll
  for (int mf = 0; mf < 4; ++mf)
    #pragma unroll
    for (int nf = 0; nf < 4; ++nf)
      acc[mf][nf] = __builtin_amdgcn_mfma_f32_16x16x32_bf16(aw0[mf], bfr[nf][0], bv[mf], 0, 0, 0);
  #pragma unroll
  for (int mf = 0; mf < 4; ++mf)
    #pragma unroll
    for (int nf = 0; nf < 4; ++nf)
      acc[mf][nf] = __builtin_amdgcn_mfma_f32_16x16x32_bf16(aw1[mf], bfr[nf][1], acc[mf][nf], 0, 0, 0);
  if (rebuild) {
    #pragma unroll
    for (int nf = 0; nf < 4; ++nf)
      #pragma unroll
      for (int kk = 0; kk < 2; ++kk) {
        bf16x8 v;
        #pragma unroll
        for (int e = 0; e < 8; ++e)
          v[e] = (__bf16)fmaxf(acc[(kk << 1) | (e >> 2)][nf][e & 3], 0.f);
        bfr[nf][kk] = v;
      }
  }
}

// Grid: 128 units x 5 blocks (unit = 256 batches).
//   s = bid%5: s<4 -> h-block: tile = unit*2+(s>>1) (128 batches), d0 = (s&1)*32.
//              s=4 -> g-block: batches unit*256..+255.
// h-block (256 thr / 4 waves): wid -> bg=wid&1 (64-batch group), dh=wid>>1 (16-d half).
//   Wave runs its 16 d SERIALLY (rolled loop), scalar result per (batch,d) -> sOut LDS.
//   Store phase after one barrier: 8-lane groups emit full 128B lines (32 d chunk).
__global__ __launch_bounds__(256, 4) void fused_nn(
    const float* __restrict__ x,
    const float* __restrict__ h_w1, const float* __restrict__ h_b1,
    const float* __restrict__ h_bh,
    const float* __restrict__ h_wo, const float* __restrict__ h_bo,
    const float* __restrict__ g_b1, const float* __restrict__ g_bh,
    const float* __restrict__ g_wo, const float* __restrict__ g_bo,
    const __bf16* __restrict__ wsH, const __bf16* __restrict__ wsG,
    float* __restrict__ out, int Btot, int nwg)
{
  __shared__ float sOut[128 * 33];   // 16.9 KB, stride 33 -> conflict-free

  const int tid  = threadIdx.x;
  const int lane = tid & 63;
  const int wid  = tid >> 6;
  const int c    = lane & 15;
  const int g4   = lane >> 4;

  // XCD-bijective swizzle (nwg % 8 == 0): contiguous unit range per XCD.
  const int b0  = blockIdx.x;
  const int bid = (b0 & 7) * (nwg >> 3) + (b0 >> 3);
  const int unit = bid / 5;
  const int s    = bid - unit * 5;

  f32x4  acc[4][4];
  bf16x8 bfr[4][2];

  if (s < 4) {
    // ---------------- h branch: 128 batches x 32 d ----------------
    const int tile = (unit << 1) + (s >> 1);
    const int d0   = (s & 1) << 5;
    const int bg   = wid & 1;
    const int dh   = wid >> 1;
    const int nb   = (tile << 7) + (bg << 6);

    for (int dl = 0; dl < 16; ++dl) {          // rolled: 16 d serially per wave
      const int d = d0 + (dh << 4) + dl;

      // h1 = relu(s * w1 + b1), built directly as B-fragments
      const float* w1p = h_w1 + (d << 6);
      const float* b1p = h_b1 + (d << 6);
      f32x4 w1v[2][2], b1v[2][2];
      #pragma unroll
      for (int kk = 0; kk < 2; ++kk)
        #pragma unroll
        for (int h = 0; h < 2; ++h) {
          int off = (kk << 5) + (g4 << 3) + (h << 2);
          w1v[kk][h] = *(const f32x4*)&w1p[off];
          b1v[kk][h] = *(const f32x4*)&b1p[off];
        }
      #pragma unroll
      for (int nf = 0; nf < 4; ++nf) {
        float sv = x[(size_t)(nb + (nf << 4) + c) * 128 + 64 + d];
        #pragma unroll
        for (int kk = 0; kk < 2; ++kk) {
          bf16x8 v;
          #pragma unroll
          for (int h = 0; h < 2; ++h)
            #pragma unroll
            for (int r = 0; r < 4; ++r)
              v[(h << 2) + r] = (__bf16)fmaxf(fmaf(sv, w1v[kk][h][r], b1v[kk][h][r]), 0.f);
          bfr[nf][kk] = v;
        }
      }

      layer(wsH + (d << 12),        h_bh + (d << 6),        lane, g4, true,  acc, bfr);
      layer(wsH + ((64 + d) << 12), h_bh + ((64 + d) << 6), lane, g4, false, acc, bfr);

      // epilogue: relu -> dot(wo[P(q)]) -> reduce over g4 groups
      const float* wo = h_wo + (d << 6);
      f32x4 wv[4];
      #pragma unroll
      for (int mf = 0; mf < 4; ++mf)
        wv[mf] = *(const f32x4*)&wo[((mf >> 1) << 5) + (g4 << 3) + ((mf & 1) << 2)];
      float p[4] = {0.f, 0.f, 0.f, 0.f};
      #pragma unroll
      for (int mf = 0; mf < 4; ++mf)
        #pragma unroll
        for (int nf = 0; nf < 4; ++nf)
          #pragma unroll
          for (int r = 0; r < 4; ++r)
            p[nf] += fmaxf(acc[mf][nf][r], 0.f) * wv[mf][r];
      #pragma unroll
      for (int nf = 0; nf < 4; ++nf) {
        p[nf] += __shfl_xor(p[nf], 16);
        p[nf] += __shfl_xor(p[nf], 32);
      }
      float sel = (g4 == 0) ? p[0] : (g4 == 1) ? p[1] : (g4 == 2) ? p[2] : p[3];
      sOut[((bg << 6) + lane) * 33 + (dh << 4) + dl] = sel + h_bo[d];
    }

    __syncthreads();
    // store phase: full 128B lines. iter i: row r = wid*32+i*8+(lane>>3), cols q*4..q*4+3
    const int q = lane & 7;
    #pragma unroll
    for (int i = 0; i < 4; ++i) {
      int r = (wid << 5) + (i << 3) + (lane >> 3);
      const float* sp = &sOut[r * 33 + (q << 2)];
      f32x4 v = { sp[0], sp[1], sp[2], sp[3] };
      *(f32x4*)&out[(size_t)((tile << 7) + r) * 64 + d0 + (q << 2)] = v;
    }

  } else {
    // ---------------- g branch: 256 batches, 3 layers ----------------
    const int nb = (unit << 8) + (wid << 6);

    #pragma unroll
    for (int nf = 0; nf < 4; ++nf) {
      const float* xr = x + (size_t)(nb + (nf << 4) + c) * 128;
      #pragma unroll
      for (int kk = 0; kk < 2; ++kk) {
        f32x4 v0 = *(const f32x4*)&xr[(kk << 5) + (g4 << 3)];
        f32x4 v1 = *(const f32x4*)&xr[(kk << 5) + (g4 << 3) + 4];
        bf16x8 v;
        #pragma unroll
        for (int r = 0; r < 4; ++r) { v[r] = (__bf16)v0[r]; v[4 + r] = (__bf16)v1[r]; }
        bfr[nf][kk] = v;
      }
    }
    layer(wsG,        g_b1,      lane, g4, true,  acc, bfr);
    layer(wsG + 4096, g_bh,      lane, g4, true,  acc, bfr);
    layer(wsG + 8192, g_bh + 64, lane, g4, false, acc, bfr);

    f32x4 wv[4];
    #pragma unroll
    for (int mf = 0; mf < 4; ++mf)
      wv[mf] = *(const f32x4*)&g_wo[((mf >> 1) << 5) + (g4 << 3) + ((mf & 1) << 2)];
    float p[4] = {0.f, 0.f, 0.f, 0.f};
    #pragma unroll
    for (int mf = 0; mf < 4; ++mf)
      #pragma unroll
      for (int nf = 0; nf < 4; ++nf)
        #pragma unroll
        for (int r = 0; r < 4; ++r)
          p[nf] += fmaxf(acc[mf][nf][r], 0.f) * wv[mf][r];
    #pragma unroll
    for (int nf = 0; nf < 4; ++nf) {
      p[nf] += __shfl_xor(p[nf], 16);
      p[nf] += __shfl_xor(p[nf], 32);
    }
    float sel = (g4 == 0) ? p[0] : (g4 == 1) ? p[1] : (g4 == 2) ? p[2] : p[3];
    out[((size_t)Btot << 6) + nb + lane] = sel + g_bo[0];
  }
}

extern "C" void kernel_launch(void* const* d_in, const int* in_sizes, int n_in,
                              void* d_out, int out_size, void* d_ws, size_t ws_size,
                              hipStream_t stream) {
  const float* x    = (const float*)d_in[0];
  const float* h_w1 = (const float*)d_in[1];
  const float* h_b1 = (const float*)d_in[2];
  const float* h_wh = (const float*)d_in[3];
  const float* h_bh = (const float*)d_in[4];
  const float* h_wo = (const float*)d_in[5];
  const float* h_bo = (const float*)d_in[6];
  const float* g_w1 = (const float*)d_in[7];
  const float* g_b1 = (const float*)d_in[8];
  const float* g_wh = (const float*)d_in[9];
  const float* g_bh = (const float*)d_in[10];
  const float* g_wo = (const float*)d_in[11];
  const float* g_bo = (const float*)d_in[12];

  __bf16* wsH = (__bf16*)d_ws;                               // 1 MB
  __bf16* wsG = (__bf16*)((char*)d_ws + 2 * 64 * 4096 * 2);  // 24 KB

  const int Btot  = in_sizes[0] / 128;    // 32768
  const int nUnit = Btot >> 8;            // 128 units of 256 batches
  const int nwg   = nUnit * 5;            // 640, % 8 == 0

  hipLaunchKernelGGL(reformat_w, dim3(2096), dim3(256), 0, stream,
                     h_wh, g_w1, g_wh, wsH, wsG);

  hipLaunchKernelGGL(fused_nn, dim3(nwg), dim3(256), 0, stream,
                     x, h_w1, h_b1, h_bh, h_wo, h_bo,
                     g_b1, g_bh, g_wo, g_bo,
                     (const __bf16*)wsH, (const __bf16*)wsG,
                     (float*)d_out, Btot, nwg);
}

// Round 7
// 86.837 us; speedup vs baseline: 2.6993x; 1.2236x over previous
//
#include <hip/hip_runtime.h>

typedef __attribute__((ext_vector_type(4))) float  f32x4;
typedef __attribute__((ext_vector_type(8))) __bf16 bf16x8;

// Chaining permutation (r3-verified). D-pos q = mf*16+g4*4+r, B-pos p = kk*32+g4*8+j.
// B_next[kk][j] = relu(acc[(kk<<1)|(j>>2)][j&3]) iff weight COLUMNS are permuted by
// P(q) = (q>>5)*32 + ((q>>2)&3)*8 + ((q>>4)&1)*4 + (q&3)  (= Q^{-1}).
__device__ __forceinline__ int Pq(int q) {
  return ((q >> 5) << 5) + (((q >> 2) & 3) << 3) + (((q >> 4) & 1) << 2) + (q & 3);
}

// ---------------- setup: weights -> A-fragment order, columns permuted by P ----------
__global__ void reformat_w(const float* __restrict__ h_wh,
                           const float* __restrict__ g_w1,
                           const float* __restrict__ g_wh,
                           __bf16* __restrict__ wsH,   // [2*64][4096]
                           __bf16* __restrict__ wsG)   // [3][4096]
{
  int i = blockIdx.x * 256 + threadIdx.x;
  int j = i & 7, lane = (i >> 3) & 63, f = (i >> 9) & 7;
  int c = lane & 15, g4 = lane >> 4, mf = f >> 1, kk = f & 1;
  int krow = (kk << 5) + (g4 << 3) + j;
  int mcol = Pq((mf << 4) + c);
  if (i < 524288) {                       // h: 2 layers * 64 heads * 4096
    int ld = i >> 12;
    wsH[i] = (__bf16)h_wh[(ld << 12) + (krow << 6) + mcol];
  } else if (i < 536576) {                // g: 3 matrices * 4096
    int t = i - 524288;
    int lg = t >> 12;
    const float* W = (lg == 0) ? g_w1 : g_wh + ((lg - 1) << 12);
    wsG[t] = (__bf16)W[(krow << 6) + mcol];
  }
}

// One MFMA layer: acc = A*B + bias; optionally rebuild B-frags from acc (relu+cvt,
// pure register renaming thanks to the P-permuted weights).
__device__ __forceinline__ void layer(const __bf16* __restrict__ wf,
                                      const float* __restrict__ bias,
                                      int lane, int g4, bool rebuild,
                                      f32x4 (&acc)[4][4], bf16x8 (&bfr)[4][2])
{
  bf16x8 aw0[4], aw1[4];
  #pragma unroll
  for (int mf = 0; mf < 4; ++mf) {
    aw0[mf] = *(const bf16x8*)&wf[((mf << 1) << 9) + (lane << 3)];
    aw1[mf] = *(const bf16x8*)&wf[(((mf << 1) | 1) << 9) + (lane << 3)];
  }
  f32x4 bv[4];
  #pragma unroll
  for (int mf = 0; mf < 4; ++mf)   // bias at D-pos q: bias[P(q)], contiguous x4
    bv[mf] = *(const f32x4*)&bias[((mf >> 1) << 5) + (g4 << 3) + ((mf & 1) << 2)];
  #pragma unroll
  for (int mf = 0; mf < 4; ++mf)
    #pragma unroll
    for (int nf = 0; nf < 4; ++nf)
      acc[mf][nf] = __builtin_amdgcn_mfma_f32_16x16x32_bf16(aw0[mf], bfr[nf][0], bv[mf], 0, 0, 0);
  #pragma unroll
  for (int mf = 0; mf < 4; ++mf)
    #pragma unroll
    for (int nf = 0; nf < 4; ++nf)
      acc[mf][nf] = __builtin_amdgcn_mfma_f32_16x16x32_bf16(aw1[mf], bfr[nf][1], acc[mf][nf], 0, 0, 0);
  if (rebuild) {
    #pragma unroll
    for (int nf = 0; nf < 4; ++nf)
      #pragma unroll
      for (int kk = 0; kk < 2; ++kk) {
        bf16x8 v;
        #pragma unroll
        for (int e = 0; e < 8; ++e)
          v[e] = (__bf16)fmaxf(acc[(kk << 1) | (e >> 2)][nf][e & 3], 0.f);
        bfr[nf][kk] = v;
      }
  }
}

// Grid: 64 units x 17 blocks (unit = 512 batches).
//   s = bid%17: s<16 -> h-block: 64 batches (bg = s>>1) x 32 d (d0 = (s&1)*32).
//               s=16 -> g-block: all 512 batches of the unit.
// h-block (512 thr / 8 waves): wave wid computes d = d0 + wid*4 + {0..3} SERIALLY
//   for the block's 64 batches; scalar result per (batch,d) -> sOut LDS.
//   Store phase after one barrier: 8-lane groups emit full 128B lines.
__global__ __launch_bounds__(512, 4) void fused_nn(
    const float* __restrict__ x,
    const float* __restrict__ h_w1, const float* __restrict__ h_b1,
    const float* __restrict__ h_bh,
    const float* __restrict__ h_wo, const float* __restrict__ h_bo,
    const float* __restrict__ g_b1, const float* __restrict__ g_bh,
    const float* __restrict__ g_wo, const float* __restrict__ g_bo,
    const __bf16* __restrict__ wsH, const __bf16* __restrict__ wsG,
    float* __restrict__ out, int Btot, int nwg)
{
  __shared__ float sOut[64 * 33];   // 8.4 KB, stride 33 -> conflict-free

  const int tid  = threadIdx.x;
  const int lane = tid & 63;
  const int wid  = tid >> 6;        // 0..7
  const int c    = lane & 15;
  const int g4   = lane >> 4;

  // XCD-bijective swizzle (nwg % 8 == 0): contiguous unit range per XCD.
  const int b0  = blockIdx.x;
  const int bid = (b0 & 7) * (nwg >> 3) + (b0 >> 3);
  const int unit = bid / 17;
  const int s    = bid - unit * 17;

  f32x4  acc[4][4];
  bf16x8 bfr[4][2];

  if (s < 16) {
    // ---------------- h branch: 64 batches x 32 d ----------------
    const int nb = (unit << 9) + ((s >> 1) << 6);   // block batch base
    const int d0 = (s & 1) << 5;

    #pragma unroll 1
    for (int dl = 0; dl < 4; ++dl) {          // 4 d serially per wave
      const int d = d0 + (wid << 2) + dl;

      // h1 = relu(s * w1 + b1), built directly as B-fragments
      const float* w1p = h_w1 + (d << 6);
      const float* b1p = h_b1 + (d << 6);
      f32x4 w1v[2][2], b1v[2][2];
      #pragma unroll
      for (int kk = 0; kk < 2; ++kk)
        #pragma unroll
        for (int h = 0; h < 2; ++h) {
          int off = (kk << 5) + (g4 << 3) + (h << 2);
          w1v[kk][h] = *(const f32x4*)&w1p[off];
          b1v[kk][h] = *(const f32x4*)&b1p[off];
        }
      #pragma unroll
      for (int nf = 0; nf < 4; ++nf) {
        float sv = x[(size_t)(nb + (nf << 4) + c) * 128 + 64 + d];
        #pragma unroll
        for (int kk = 0; kk < 2; ++kk) {
          bf16x8 v;
          #pragma unroll
          for (int h = 0; h < 2; ++h)
            #pragma unroll
            for (int r = 0; r < 4; ++r)
              v[(h << 2) + r] = (__bf16)fmaxf(fmaf(sv, w1v[kk][h][r], b1v[kk][h][r]), 0.f);
          bfr[nf][kk] = v;
        }
      }

      layer(wsH + (d << 12),        h_bh + (d << 6),        lane, g4, true,  acc, bfr);
      layer(wsH + ((64 + d) << 12), h_bh + ((64 + d) << 6), lane, g4, false, acc, bfr);

      // epilogue: relu -> dot(wo[P(q)]) -> reduce over g4 groups
      const float* wo = h_wo + (d << 6);
      f32x4 wv[4];
      #pragma unroll
      for (int mf = 0; mf < 4; ++mf)
        wv[mf] = *(const f32x4*)&wo[((mf >> 1) << 5) + (g4 << 3) + ((mf & 1) << 2)];
      float p[4] = {0.f, 0.f, 0.f, 0.f};
      #pragma unroll
      for (int mf = 0; mf < 4; ++mf)
        #pragma unroll
        for (int nf = 0; nf < 4; ++nf)
          #pragma unroll
          for (int r = 0; r < 4; ++r)
            p[nf] += fmaxf(acc[mf][nf][r], 0.f) * wv[mf][r];
      #pragma unroll
      for (int nf = 0; nf < 4; ++nf) {
        p[nf] += __shfl_xor(p[nf], 16);
        p[nf] += __shfl_xor(p[nf], 32);
      }
      float sel = (g4 == 0) ? p[0] : (g4 == 1) ? p[1] : (g4 == 2) ? p[2] : p[3];
      sOut[lane * 33 + (wid << 2) + dl] = sel + h_bo[d];
    }

    __syncthreads();
    // store phase: full 128B lines; 8-lane group per batch row
    {
      const int r = tid >> 3, q = tid & 7;
      const float* sp = &sOut[r * 33 + (q << 2)];
      f32x4 v = { sp[0], sp[1], sp[2], sp[3] };
      *(f32x4*)&out[(size_t)(nb + r) * 64 + d0 + (q << 2)] = v;
    }

  } else {
    // ---------------- g branch: 512 batches, 3 layers ----------------
    const int nb = (unit << 9) + (wid << 6);

    #pragma unroll
    for (int nf = 0; nf < 4; ++nf) {
      const float* xr = x + (size_t)(nb + (nf << 4) + c) * 128;
      #pragma unroll
      for (int kk = 0; kk < 2; ++kk) {
        f32x4 v0 = *(const f32x4*)&xr[(kk << 5) + (g4 << 3)];
        f32x4 v1 = *(const f32x4*)&xr[(kk << 5) + (g4 << 3) + 4];
        bf16x8 v;
        #pragma unroll
        for (int r = 0; r < 4; ++r) { v[r] = (__bf16)v0[r]; v[4 + r] = (__bf16)v1[r]; }
        bfr[nf][kk] = v;
      }
    }
    layer(wsG,        g_b1,      lane, g4, true,  acc, bfr);
    layer(wsG + 4096, g_bh,      lane, g4, true,  acc, bfr);
    layer(wsG + 8192, g_bh + 64, lane, g4, false, acc, bfr);

    f32x4 wv[4];
    #pragma unroll
    for (int mf = 0; mf < 4; ++mf)
      wv[mf] = *(const f32x4*)&g_wo[((mf >> 1) << 5) + (g4 << 3) + ((mf & 1) << 2)];
    float p[4] = {0.f, 0.f, 0.f, 0.f};
    #pragma unroll
    for (int mf = 0; mf < 4; ++mf)
      #pragma unroll
      for (int nf = 0; nf < 4; ++nf)
        #pragma unroll
        for (int r = 0; r < 4; ++r)
          p[nf] += fmaxf(acc[mf][nf][r], 0.f) * wv[mf][r];
    #pragma unroll
    for (int nf = 0; nf < 4; ++nf) {
      p[nf] += __shfl_xor(p[nf], 16);
      p[nf] += __shfl_xor(p[nf], 32);
    }
    float sel = (g4 == 0) ? p[0] : (g4 == 1) ? p[1] : (g4 == 2) ? p[2] : p[3];
    out[((size_t)Btot << 6) + nb + lane] = sel + g_bo[0];
  }
}

extern "C" void kernel_launch(void* const* d_in, const int* in_sizes, int n_in,
                              void* d_out, int out_size, void* d_ws, size_t ws_size,
                              hipStream_t stream) {
  const float* x    = (const float*)d_in[0];
  const float* h_w1 = (const float*)d_in[1];
  const float* h_b1 = (const float*)d_in[2];
  const float* h_wh = (const float*)d_in[3];
  const float* h_bh = (const float*)d_in[4];
  const float* h_wo = (const float*)d_in[5];
  const float* h_bo = (const float*)d_in[6];
  const float* g_w1 = (const float*)d_in[7];
  const float* g_b1 = (const float*)d_in[8];
  const float* g_wh = (const float*)d_in[9];
  const float* g_bh = (const float*)d_in[10];
  const float* g_wo = (const float*)d_in[11];
  const float* g_bo = (const float*)d_in[12];

  __bf16* wsH = (__bf16*)d_ws;                               // 1 MB
  __bf16* wsG = (__bf16*)((char*)d_ws + 2 * 64 * 4096 * 2);  // 24 KB

  const int Btot  = in_sizes[0] / 128;    // 32768
  const int nUnit = Btot >> 9;            // 64 units of 512 batches
  const int nwg   = nUnit * 17;           // 1088, % 8 == 0

  hipLaunchKernelGGL(reformat_w, dim3(2096), dim3(256), 0, stream,
                     h_wh, g_w1, g_wh, wsH, wsG);

  hipLaunchKernelGGL(fused_nn, dim3(nwg), dim3(512), 0, stream,
                     x, h_w1, h_b1, h_bh, h_wo, h_bo,
                     g_b1, g_bh, g_wo, g_bo,
                     (const __bf16*)wsH, (const __bf16*)wsG,
                     (float*)d_out, Btot, nwg);
}

// Round 8
// 83.392 us; speedup vs baseline: 2.8108x; 1.0413x over previous
//
#include <hip/hip_runtime.h>

typedef __attribute__((ext_vector_type(4))) float  f32x4;
typedef __attribute__((ext_vector_type(8))) __bf16 bf16x8;

// Chaining permutation (r3-verified). D-pos q = mf*16+g4*4+r, B-pos p = kk*32+g4*8+j.
// B_next[kk][j] = relu(acc[(kk<<1)|(j>>2)][j&3]) iff weight COLUMNS are permuted by
// P(q) = (q>>5)*32 + ((q>>2)&3)*8 + ((q>>4)&1)*4 + (q&3)  (= Q^{-1}, P∘Q = id).
__device__ __forceinline__ int Pq(int q) {
  return ((q >> 5) << 5) + (((q >> 2) & 3) << 3) + (((q >> 4) & 1) << 2) + (q & 3);
}
__device__ __forceinline__ float cut16(float v) {   // upper-bf16 truncation (exact)
  return __uint_as_float(__float_as_uint(v) & 0xFFFF0000u);
}

#define HSZ 11264   // per-d bf16 elements in wsH: W1'[4x512] | L0[8x512] | L1[8x512] | wo[2x512]

// ---------------- setup: all h weights -> MFMA A-fragment order ----------------
// W1' combined layer (K=32, kk=0 only): A rows k = 0:w1_hi 1:b1_hi 2:w1_hi 3:w1_lo 4:b1_lo,
//   columns P-permuted.  B side supplies {s_hi, 1, s_lo, s_hi, 1}  =>  D = w1*s + b1 (~exact).
// wo frags: A row m=0 = wo_hi[k], m=1 = wo_lo[k], k identity (B comes from rebuild => identity).
__global__ void reformat_w(const float* __restrict__ h_w1, const float* __restrict__ h_b1,
                           const float* __restrict__ h_wh, const float* __restrict__ h_wo,
                           const float* __restrict__ g_w1, const float* __restrict__ g_wh,
                           __bf16* __restrict__ wsH, __bf16* __restrict__ wsG)
{
  int i = blockIdx.x * 256 + threadIdx.x;
  if (i < 64 * HSZ) {
    int d = i / HSZ, o = i - d * HSZ;
    int e = o & 511, j = e & 7, lane = e >> 3, c = lane & 15, g4 = lane >> 4;
    float val = 0.f;
    if (o < 2048) {                    // W1' region: frag index = mf
      int mf = o >> 9;
      if (g4 == 0 && j <= 4) {
        int Pc = Pq((mf << 4) | c);
        float w1 = h_w1[(d << 6) + Pc], b1 = h_b1[(d << 6) + Pc];
        float w1h = cut16(w1), b1h = cut16(b1);
        val = (j == 1) ? b1h : (j == 3) ? (w1 - w1h) : (j == 4) ? (b1 - b1h) : w1h;
      }
    } else if (o < 10240) {            // hidden layers l = 0,1
      int o2 = o - 2048;
      int l = o2 >> 12, f = (o2 >> 9) & 7;
      int mf = f >> 1, kk = f & 1;
      int krow = (kk << 5) + (g4 << 3) + j;
      int mcol = Pq((mf << 4) | c);
      val = h_wh[(((l << 6) + d) << 12) + (krow << 6) + mcol];
    } else {                           // wo region: frag index = kk
      int o3 = o - 10240;
      int kk = o3 >> 9;
      int k = (kk << 5) + (g4 << 3) + j;
      float wo = h_wo[(d << 6) + k];
      float woh = cut16(wo);
      val = (c == 0) ? woh : (c == 1) ? (wo - woh) : 0.f;
    }
    wsH[i] = (__bf16)val;
  } else if (i < 64 * HSZ + 12288) {   // g: 3 matrices, plain A-frag order (as r7)
    int t = i - 64 * HSZ;
    int j = t & 7, lane = (t >> 3) & 63, f = (t >> 9) & 7;
    int c = lane & 15, g4 = lane >> 4, mf = f >> 1, kk = f & 1;
    int krow = (kk << 5) + (g4 << 3) + j;
    int mcol = Pq((mf << 4) + c);
    int lg = t >> 12;
    const float* W = (lg == 0) ? g_w1 : g_wh + ((lg - 1) << 12);
    wsG[t] = (__bf16)W[(krow << 6) + mcol];
  }
}

// relu + downcast acc -> B-fragments (pure register renaming via P-permuted weights)
__device__ __forceinline__ void rebuild(const f32x4 (&acc)[4][4], bf16x8 (&bfr)[4][2]) {
  #pragma unroll
  for (int nf = 0; nf < 4; ++nf)
    #pragma unroll
    for (int kk = 0; kk < 2; ++kk) {
      bf16x8 v;
      #pragma unroll
      for (int e = 0; e < 8; ++e)
        v[e] = (__bf16)fmaxf(acc[(kk << 1) | (e >> 2)][nf][e & 3], 0.f);
      bfr[nf][kk] = v;
    }
}

// One 64x64 MFMA layer: acc = W*B + bias(C operand); optional rebuild.
__device__ __forceinline__ void layer(const __bf16* __restrict__ wf,
                                      const float* __restrict__ bias,
                                      int lane, int g4, bool do_rebuild,
                                      f32x4 (&acc)[4][4], bf16x8 (&bfr)[4][2])
{
  bf16x8 aw0[4], aw1[4];
  #pragma unroll
  for (int mf = 0; mf < 4; ++mf) {
    aw0[mf] = *(const bf16x8*)&wf[((mf << 1) << 9) + (lane << 3)];
    aw1[mf] = *(const bf16x8*)&wf[(((mf << 1) | 1) << 9) + (lane << 3)];
  }
  f32x4 bv[4];
  #pragma unroll
  for (int mf = 0; mf < 4; ++mf)   // bias at D-pos q: bias[P(q)], contiguous x4
    bv[mf] = *(const f32x4*)&bias[((mf >> 1) << 5) + (g4 << 3) + ((mf & 1) << 2)];
  #pragma unroll
  for (int mf = 0; mf < 4; ++mf)
    #pragma unroll
    for (int nf = 0; nf < 4; ++nf)
      acc[mf][nf] = __builtin_amdgcn_mfma_f32_16x16x32_bf16(aw0[mf], bfr[nf][0], bv[mf], 0, 0, 0);
  #pragma unroll
  for (int mf = 0; mf < 4; ++mf)
    #pragma unroll
    for (int nf = 0; nf < 4; ++nf)
      acc[mf][nf] = __builtin_amdgcn_mfma_f32_16x16x32_bf16(aw1[mf], bfr[nf][1], acc[mf][nf], 0, 0, 0);
  if (do_rebuild) rebuild(acc, bfr);
}

// Grid: 64 units x 17 blocks (unit = 512 batches), as r7.
//   s<16 -> h-block: 64 batches x 32 d; 8 waves, wave owns d = d0+wid*4+{0..3} serially.
//   s=16 -> g-block: 512 batches.
__global__ __launch_bounds__(512, 4) void fused_nn(
    const float* __restrict__ x,
    const float* __restrict__ h_bh, const float* __restrict__ h_bo,
    const float* __restrict__ g_b1, const float* __restrict__ g_bh,
    const float* __restrict__ g_wo, const float* __restrict__ g_bo,
    const __bf16* __restrict__ wsH, const __bf16* __restrict__ wsG,
    float* __restrict__ out, int Btot, int nwg)
{
  __shared__ float sOut[64 * 33];   // 8.4 KB, conflict-free

  const int tid  = threadIdx.x;
  const int lane = tid & 63;
  const int wid  = tid >> 6;
  const int c    = lane & 15;
  const int g4   = lane >> 4;

  const int b0  = blockIdx.x;
  const int bid = (b0 & 7) * (nwg >> 3) + (b0 >> 3);   // XCD-bijective swizzle
  const int unit = bid / 17;
  const int s    = bid - unit * 17;

  f32x4  acc[4][4];
  bf16x8 bfr[4][2];
  const f32x4 z = {0.f, 0.f, 0.f, 0.f};

  if (s < 16) {
    // ---------------- h branch: 64 batches x 32 d ----------------
    const int nb = (unit << 9) + ((s >> 1) << 6);
    const int d0 = (s & 1) << 5;

    #pragma unroll 1
    for (int dl = 0; dl < 4; ++dl) {
      const int d = d0 + (wid << 2) + dl;
      const __bf16* base = wsH + d * HSZ;

      // B0 frags: {s_hi, 1, s_lo, s_hi, 1, 0, 0, 0}; rows k>=5 of A are zero, so
      // lanes g4!=0 need no special-casing.
      #pragma unroll
      for (int nf = 0; nf < 4; ++nf) {
        float sv = 0.f;
        if (g4 == 0) sv = x[(size_t)(nb + (nf << 4) + c) * 128 + 64 + d];
        float shf = cut16(sv);
        __bf16 sh = (__bf16)shf, sl = (__bf16)(sv - shf);
        bf16x8 v = {};
        v[0] = sh; v[1] = (__bf16)1.0f; v[2] = sl; v[3] = sh; v[4] = (__bf16)1.0f;
        bfr[nf][0] = v;
      }

      // L0': h1 = w1*s + b1 via MFMA (bias folded into A rows), then relu-rebuild
      {
        bf16x8 a1[4];
        #pragma unroll
        for (int mf = 0; mf < 4; ++mf)
          a1[mf] = *(const bf16x8*)&base[(mf << 9) + (lane << 3)];
        #pragma unroll
        for (int mf = 0; mf < 4; ++mf)
          #pragma unroll
          for (int nf = 0; nf < 4; ++nf)
            acc[mf][nf] = __builtin_amdgcn_mfma_f32_16x16x32_bf16(a1[mf], bfr[nf][0], z, 0, 0, 0);
        rebuild(acc, bfr);
      }

      layer(base + 2048, h_bh + (d << 6),        lane, g4, true, acc, bfr);
      layer(base + 6144, h_bh + ((64 + d) << 6), lane, g4, true, acc, bfr);

      // epilogue: out = wo . relu(h3) via MFMA, wo split hi/lo in A rows m=0/1
      {
        bf16x8 wo0 = *(const bf16x8*)&base[10240 + (lane << 3)];
        bf16x8 wo1 = *(const bf16x8*)&base[10240 + 512 + (lane << 3)];
        float bo = h_bo[d];
        #pragma unroll
        for (int nf = 0; nf < 4; ++nf) {
          f32x4 e2 = __builtin_amdgcn_mfma_f32_16x16x32_bf16(wo0, bfr[nf][0], z, 0, 0, 0);
          e2 = __builtin_amdgcn_mfma_f32_16x16x32_bf16(wo1, bfr[nf][1], e2, 0, 0, 0);
          if (g4 == 0)   // D rows 0 (wo_hi.h3) and 1 (wo_lo.h3) live in g4==0 lanes
            sOut[((nf << 4) + c) * 33 + (wid << 2) + dl] = e2[0] + e2[1] + bo;
        }
      }
    }

    __syncthreads();
    // store phase: full 128B lines; 8-lane group per batch row (r7-verified)
    {
      const int r = tid >> 3, q = tid & 7;
      const float* sp = &sOut[r * 33 + (q << 2)];
      f32x4 v = { sp[0], sp[1], sp[2], sp[3] };
      *(f32x4*)&out[(size_t)(nb + r) * 64 + d0 + (q << 2)] = v;
    }

  } else {
    // ---------------- g branch: 512 batches, 3 layers (r7-verified) ----------------
    const int nb = (unit << 9) + (wid << 6);

    #pragma unroll
    for (int nf = 0; nf < 4; ++nf) {
      const float* xr = x + (size_t)(nb + (nf << 4) + c) * 128;
      #pragma unroll
      for (int kk = 0; kk < 2; ++kk) {
        f32x4 v0 = *(const f32x4*)&xr[(kk << 5) + (g4 << 3)];
        f32x4 v1 = *(const f32x4*)&xr[(kk << 5) + (g4 << 3) + 4];
        bf16x8 v;
        #pragma unroll
        for (int r = 0; r < 4; ++r) { v[r] = (__bf16)v0[r]; v[4 + r] = (__bf16)v1[r]; }
        bfr[nf][kk] = v;
      }
    }
    layer(wsG,        g_b1,      lane, g4, true,  acc, bfr);
    layer(wsG + 4096, g_bh,      lane, g4, true,  acc, bfr);
    layer(wsG + 8192, g_bh + 64, lane, g4, false, acc, bfr);

    f32x4 wv[4];
    #pragma unroll
    for (int mf = 0; mf < 4; ++mf)
      wv[mf] = *(const f32x4*)&g_wo[((mf >> 1) << 5) + (g4 << 3) + ((mf & 1) << 2)];
    float p[4] = {0.f, 0.f, 0.f, 0.f};
    #pragma unroll
    for (int mf = 0; mf < 4; ++mf)
      #pragma unroll
      for (int nf = 0; nf < 4; ++nf)
        #pragma unroll
        for (int r = 0; r < 4; ++r)
          p[nf] += fmaxf(acc[mf][nf][r], 0.f) * wv[mf][r];
    #pragma unroll
    for (int nf = 0; nf < 4; ++nf) {
      p[nf] += __shfl_xor(p[nf], 16);
      p[nf] += __shfl_xor(p[nf], 32);
    }
    float sel = (g4 == 0) ? p[0] : (g4 == 1) ? p[1] : (g4 == 2) ? p[2] : p[3];
    out[((size_t)Btot << 6) + nb + lane] = sel + g_bo[0];
  }
}

extern "C" void kernel_launch(void* const* d_in, const int* in_sizes, int n_in,
                              void* d_out, int out_size, void* d_ws, size_t ws_size,
                              hipStream_t stream) {
  const float* x    = (const float*)d_in[0];
  const float* h_w1 = (const float*)d_in[1];
  const float* h_b1 = (const float*)d_in[2];
  const float* h_wh = (const float*)d_in[3];
  const float* h_bh = (const float*)d_in[4];
  const float* h_wo = (const float*)d_in[5];
  const float* h_bo = (const float*)d_in[6];
  const float* g_w1 = (const float*)d_in[7];
  const float* g_b1 = (const float*)d_in[8];
  const float* g_wh = (const float*)d_in[9];
  const float* g_bh = (const float*)d_in[10];
  const float* g_wo = (const float*)d_in[11];
  const float* g_bo = (const float*)d_in[12];

  __bf16* wsH = (__bf16*)d_ws;                       // 64*11264 bf16 = 1.44 MB
  __bf16* wsG = wsH + 64 * HSZ;                      // 3*4096 bf16 = 24 KB

  const int Btot  = in_sizes[0] / 128;    // 32768
  const int nUnit = Btot >> 9;            // 64 units of 512 batches
  const int nwg   = nUnit * 17;           // 1088, % 8 == 0

  // (64*HSZ + 12288) / 256 = 2864 blocks
  hipLaunchKernelGGL(reformat_w, dim3(2864), dim3(256), 0, stream,
                     h_w1, h_b1, h_wh, h_wo, g_w1, g_wh, wsH, wsG);

  hipLaunchKernelGGL(fused_nn, dim3(nwg), dim3(512), 0, stream,
                     x, h_bh, h_bo,
                     g_b1, g_bh, g_wo, g_bo,
                     (const __bf16*)wsH, (const __bf16*)wsG,
                     (float*)d_out, Btot, nwg);
}

// Round 9
// 70.120 us; speedup vs baseline: 3.3429x; 1.1893x over previous
//
#include <hip/hip_runtime.h>
#include <stdint.h>

typedef __attribute__((ext_vector_type(4))) float  f32x4;
typedef __attribute__((ext_vector_type(8))) __bf16 bf16x8;

// Chaining permutation (r3-verified). D-pos q = mf*16+g4*4+r, B-pos p = kk*32+g4*8+j.
// B_next[kk][j] = relu(acc[(kk<<1)|(j>>2)][j&3]) iff weight COLUMNS are permuted by
// P(q) = (q>>5)*32 + ((q>>2)&3)*8 + ((q>>4)&1)*4 + (q&3)  (= Q^{-1}, P∘Q = id).
__device__ __forceinline__ int Pq(int q) {
  return ((q >> 5) << 5) + (((q >> 2) & 3) << 3) + (((q >> 4) & 1) << 2) + (q & 3);
}
__device__ __forceinline__ float cut16(float v) {   // upper-bf16 truncation (exact)
  return __uint_as_float(__float_as_uint(v) & 0xFFFF0000u);
}

#define HSZ 11264   // per-d bf16 elems in wsH: W1'[4x512] | L0[8x512] | L1[8x512] | wo[2x512]

// global -> LDS direct copy, 16B per lane (dest = uniform base + lane*16)
#define GL2LDS(gp, lp) __builtin_amdgcn_global_load_lds(                     \
    (const __attribute__((address_space(1))) uint32_t*)(gp),                 \
    (__attribute__((address_space(3))) uint32_t*)(lp), 16, 0, 0)

// ---------------- setup: all h weights -> MFMA A-fragment order (r8-verified) --------
__global__ void reformat_w(const float* __restrict__ h_w1, const float* __restrict__ h_b1,
                           const float* __restrict__ h_wh, const float* __restrict__ h_wo,
                           const float* __restrict__ g_w1, const float* __restrict__ g_wh,
                           __bf16* __restrict__ wsH, __bf16* __restrict__ wsG)
{
  int i = blockIdx.x * 256 + threadIdx.x;
  if (i < 64 * HSZ) {
    int d = i / HSZ, o = i - d * HSZ;
    int e = o & 511, j = e & 7, lane = e >> 3, c = lane & 15, g4 = lane >> 4;
    float val = 0.f;
    if (o < 2048) {                    // W1' region: A rows 0:w1_hi 1:b1_hi 2:w1_hi 3:w1_lo 4:b1_lo
      int mf = o >> 9;
      if (g4 == 0 && j <= 4) {
        int Pc = Pq((mf << 4) | c);
        float w1 = h_w1[(d << 6) + Pc], b1 = h_b1[(d << 6) + Pc];
        float w1h = cut16(w1), b1h = cut16(b1);
        val = (j == 1) ? b1h : (j == 3) ? (w1 - w1h) : (j == 4) ? (b1 - b1h) : w1h;
      }
    } else if (o < 10240) {            // hidden layers l = 0,1
      int o2 = o - 2048;
      int l = o2 >> 12, f = (o2 >> 9) & 7;
      int mf = f >> 1, kk = f & 1;
      int krow = (kk << 5) + (g4 << 3) + j;
      int mcol = Pq((mf << 4) | c);
      val = h_wh[(((l << 6) + d) << 12) + (krow << 6) + mcol];
    } else {                           // wo region: A row m=0 wo_hi, m=1 wo_lo
      int o3 = o - 10240;
      int kk = o3 >> 9;
      int k = (kk << 5) + (g4 << 3) + j;
      float wo = h_wo[(d << 6) + k];
      float woh = cut16(wo);
      val = (c == 0) ? woh : (c == 1) ? (wo - woh) : 0.f;
    }
    wsH[i] = (__bf16)val;
  } else if (i < 64 * HSZ + 12288) {   // g: 3 matrices, plain A-frag order
    int t = i - 64 * HSZ;
    int j = t & 7, lane = (t >> 3) & 63, f = (t >> 9) & 7;
    int c = lane & 15, g4 = lane >> 4, mf = f >> 1, kk = f & 1;
    int krow = (kk << 5) + (g4 << 3) + j;
    int mcol = Pq((mf << 4) + c);
    int lg = t >> 12;
    const float* W = (lg == 0) ? g_w1 : g_wh + ((lg - 1) << 12);
    wsG[t] = (__bf16)W[(krow << 6) + mcol];
  }
}

// relu + downcast acc -> B-fragments (pure register renaming via P-permuted weights)
__device__ __forceinline__ void rebuild(const f32x4 (&acc)[4][4], bf16x8 (&bfr)[4][2]) {
  #pragma unroll
  for (int nf = 0; nf < 4; ++nf)
    #pragma unroll
    for (int kk = 0; kk < 2; ++kk) {
      bf16x8 v;
      #pragma unroll
      for (int e = 0; e < 8; ++e)
        v[e] = (__bf16)fmaxf(acc[(kk << 1) | (e >> 2)][nf][e & 3], 0.f);
      bfr[nf][kk] = v;
    }
}

// One 64x64 MFMA layer: acc = W*B + bias(C operand); optional rebuild.
// wf may point into LDS (h path: ds_read_b128) or global (g path).
__device__ __forceinline__ void layer(const __bf16* __restrict__ wf,
                                      const float* __restrict__ bias,
                                      int lane, int g4, bool do_rebuild,
                                      f32x4 (&acc)[4][4], bf16x8 (&bfr)[4][2])
{
  bf16x8 aw0[4], aw1[4];
  #pragma unroll
  for (int mf = 0; mf < 4; ++mf) {
    aw0[mf] = *(const bf16x8*)&wf[((mf << 1) << 9) + (lane << 3)];
    aw1[mf] = *(const bf16x8*)&wf[(((mf << 1) | 1) << 9) + (lane << 3)];
  }
  f32x4 bv[4];
  #pragma unroll
  for (int mf = 0; mf < 4; ++mf)   // bias at D-pos q: bias[P(q)], contiguous x4
    bv[mf] = *(const f32x4*)&bias[((mf >> 1) << 5) + (g4 << 3) + ((mf & 1) << 2)];
  #pragma unroll
  for (int mf = 0; mf < 4; ++mf)
    #pragma unroll
    for (int nf = 0; nf < 4; ++nf)
      acc[mf][nf] = __builtin_amdgcn_mfma_f32_16x16x32_bf16(aw0[mf], bfr[nf][0], bv[mf], 0, 0, 0);
  #pragma unroll
  for (int mf = 0; mf < 4; ++mf)
    #pragma unroll
    for (int nf = 0; nf < 4; ++nf)
      acc[mf][nf] = __builtin_amdgcn_mfma_f32_16x16x32_bf16(aw1[mf], bfr[nf][1], acc[mf][nf], 0, 0, 0);
  if (do_rebuild) rebuild(acc, bfr);
}

// Stage one d's full fragment set (22 x 1KB chunks) into LDS; waves split chunks.
__device__ __forceinline__ void stageW(const __bf16* __restrict__ src, __bf16* dst,
                                       int wid, int lane) {
  #pragma unroll
  for (int u = 0; u < 6; ++u) {
    int ch = (u << 2) + wid;                 // wave-uniform chunk id
    if (ch < 22)
      GL2LDS(src + (ch << 9) + (lane << 3), dst + (ch << 9));
  }
}

// Grid: 128 units x 5 blocks (unit = 256 batches).
//   s<4  -> h-block: 256 batches x 16 d (d0 = s*16); 4 waves ALL on the same d
//           (64 batches each), d looped 16x with double-buffered LDS weight staging.
//   s==4 -> g-block: 256 batches, 3 layers (weights straight from L2 as before).
__global__ __launch_bounds__(256, 2) void fused_nn(
    const float* __restrict__ x,
    const float* __restrict__ h_bh, const float* __restrict__ h_bo,
    const float* __restrict__ g_b1, const float* __restrict__ g_bh,
    const float* __restrict__ g_wo, const float* __restrict__ g_bo,
    const __bf16* __restrict__ wsH, const __bf16* __restrict__ wsG,
    float* __restrict__ out, int Btot, int nwg)
{
  __shared__ __bf16 sW[2][HSZ];      // 2 x 22528 B double-buffered weight stage
  __shared__ float  sOut[256 * 17];  // 17408 B, stride 17 -> conflict-free

  const int tid  = threadIdx.x;
  const int lane = tid & 63;
  const int wid  = tid >> 6;
  const int c    = lane & 15;
  const int g4   = lane >> 4;

  const int b0  = blockIdx.x;
  const int bid = (b0 & 7) * (nwg >> 3) + (b0 >> 3);   // XCD-bijective swizzle
  const int unit = bid / 5;
  const int s    = bid - unit * 5;

  const f32x4 z = {0.f, 0.f, 0.f, 0.f};

  if (s < 4) {
    // ---------------- h branch ----------------
    const int d0  = s << 4;
    const int nbw = (unit << 8) + (wid << 6);   // wave's 64-batch base

    stageW(wsH + d0 * HSZ, sW[0], wid, lane);   // prologue stage d0
    __syncthreads();

    #pragma unroll 1
    for (int tg = 0; tg < 4; ++tg) {
      // x for the next 4 d, one f32x4 per nf (contiguous in d)
      f32x4 xq[4];
      #pragma unroll
      for (int nf = 0; nf < 4; ++nf)
        xq[nf] = *(const f32x4*)&x[(size_t)(nbw + (nf << 4) + c) * 128 + 64 + d0 + (tg << 2)];

      #pragma unroll
      for (int ti = 0; ti < 4; ++ti) {
        const int t = (tg << 2) + ti;
        const int d = d0 + t;
        const __bf16* Wb = sW[ti & 1];

        if (t < 15) stageW(wsH + (d + 1) * HSZ, sW[1 - (ti & 1)], wid, lane);

        // B0 frags: {s_hi, 1, s_lo, s_hi, 1, 0,0,0} (A rows k>=5 are zero)
        bf16x8 b0[4];
        #pragma unroll
        for (int nf = 0; nf < 4; ++nf) {
          float sv  = xq[nf][ti];               // static index (rule #20)
          float shf = cut16(sv);
          bf16x8 v = {};
          v[0] = (__bf16)shf; v[1] = (__bf16)1.0f; v[2] = (__bf16)(sv - shf);
          v[3] = (__bf16)shf; v[4] = (__bf16)1.0f;
          b0[nf] = v;
        }

        f32x4  acc[4][4];
        bf16x8 bfr[4][2];
        // L0': h1 = w1*s + b1 via MFMA, then relu-rebuild
        {
          bf16x8 a1[4];
          #pragma unroll
          for (int mf = 0; mf < 4; ++mf)
            a1[mf] = *(const bf16x8*)&Wb[(mf << 9) + (lane << 3)];
          #pragma unroll
          for (int mf = 0; mf < 4; ++mf)
            #pragma unroll
            for (int nf = 0; nf < 4; ++nf)
              acc[mf][nf] = __builtin_amdgcn_mfma_f32_16x16x32_bf16(a1[mf], b0[nf], z, 0, 0, 0);
          rebuild(acc, bfr);
        }
        layer(Wb + 2048, h_bh + (d << 6),        lane, g4, true, acc, bfr);
        layer(Wb + 6144, h_bh + ((64 + d) << 6), lane, g4, true, acc, bfr);

        // epilogue: out_d = wo . relu(h3) via MFMA (wo split hi/lo in rows m=0/1)
        {
          bf16x8 wo0 = *(const bf16x8*)&Wb[10240 + (lane << 3)];
          bf16x8 wo1 = *(const bf16x8*)&Wb[10752 + (lane << 3)];
          float bo = h_bo[d];
          #pragma unroll
          for (int nf = 0; nf < 4; ++nf) {
            f32x4 e2 = __builtin_amdgcn_mfma_f32_16x16x32_bf16(wo0, bfr[nf][0], z, 0, 0, 0);
            e2 = __builtin_amdgcn_mfma_f32_16x16x32_bf16(wo1, bfr[nf][1], e2, 0, 0, 0);
            if (g4 == 0)
              sOut[((wid << 6) + (nf << 4) + c) * 17 + t] = e2[0] + e2[1] + bo;
          }
        }
        __syncthreads();   // stage(d+1) drained + all waves done reading Wb
      }
    }

    // store phase: 64B sector per batch; 4-lane groups, fully covered sectors
    #pragma unroll
    for (int i = 0; i < 4; ++i) {
      int r = (i << 6) + (tid >> 2), q = tid & 3;
      const float* sp = &sOut[r * 17 + (q << 2)];
      f32x4 v = { sp[0], sp[1], sp[2], sp[3] };
      *(f32x4*)&out[(size_t)((unit << 8) + r) * 64 + d0 + (q << 2)] = v;
    }

  } else {
    // ---------------- g branch: 256 batches, 3 layers (r7-verified) ----------------
    const int nb = (unit << 8) + (wid << 6);

    f32x4  acc[4][4];
    bf16x8 bfr[4][2];
    #pragma unroll
    for (int nf = 0; nf < 4; ++nf) {
      const float* xr = x + (size_t)(nb + (nf << 4) + c) * 128;
      #pragma unroll
      for (int kk = 0; kk < 2; ++kk) {
        f32x4 v0 = *(const f32x4*)&xr[(kk << 5) + (g4 << 3)];
        f32x4 v1 = *(const f32x4*)&xr[(kk << 5) + (g4 << 3) + 4];
        bf16x8 v;
        #pragma unroll
        for (int r = 0; r < 4; ++r) { v[r] = (__bf16)v0[r]; v[4 + r] = (__bf16)v1[r]; }
        bfr[nf][kk] = v;
      }
    }
    layer(wsG,        g_b1,      lane, g4, true,  acc, bfr);
    layer(wsG + 4096, g_bh,      lane, g4, true,  acc, bfr);
    layer(wsG + 8192, g_bh + 64, lane, g4, false, acc, bfr);

    f32x4 wv[4];
    #pragma unroll
    for (int mf = 0; mf < 4; ++mf)
      wv[mf] = *(const f32x4*)&g_wo[((mf >> 1) << 5) + (g4 << 3) + ((mf & 1) << 2)];
    float p[4] = {0.f, 0.f, 0.f, 0.f};
    #pragma unroll
    for (int mf = 0; mf < 4; ++mf)
      #pragma unroll
      for (int nf = 0; nf < 4; ++nf)
        #pragma unroll
        for (int r = 0; r < 4; ++r)
          p[nf] += fmaxf(acc[mf][nf][r], 0.f) * wv[mf][r];
    #pragma unroll
    for (int nf = 0; nf < 4; ++nf) {
      p[nf] += __shfl_xor(p[nf], 16);
      p[nf] += __shfl_xor(p[nf], 32);
    }
    float sel = (g4 == 0) ? p[0] : (g4 == 1) ? p[1] : (g4 == 2) ? p[2] : p[3];
    out[((size_t)Btot << 6) + nb + lane] = sel + g_bo[0];
  }
}

extern "C" void kernel_launch(void* const* d_in, const int* in_sizes, int n_in,
                              void* d_out, int out_size, void* d_ws, size_t ws_size,
                              hipStream_t stream) {
  const float* x    = (const float*)d_in[0];
  const float* h_w1 = (const float*)d_in[1];
  const float* h_b1 = (const float*)d_in[2];
  const float* h_wh = (const float*)d_in[3];
  const float* h_bh = (const float*)d_in[4];
  const float* h_wo = (const float*)d_in[5];
  const float* h_bo = (const float*)d_in[6];
  const float* g_w1 = (const float*)d_in[7];
  const float* g_b1 = (const float*)d_in[8];
  const float* g_wh = (const float*)d_in[9];
  const float* g_bh = (const float*)d_in[10];
  const float* g_wo = (const float*)d_in[11];
  const float* g_bo = (const float*)d_in[12];

  __bf16* wsH = (__bf16*)d_ws;                       // 64*HSZ bf16 = 1.44 MB
  __bf16* wsG = wsH + 64 * HSZ;                      // 3*4096 bf16 = 24 KB

  const int Btot  = in_sizes[0] / 128;    // 32768
  const int nUnit = Btot >> 8;            // 128 units of 256 batches
  const int nwg   = nUnit * 5;            // 640, % 8 == 0

  // (64*HSZ + 12288) / 256 = 2864 blocks
  hipLaunchKernelGGL(reformat_w, dim3(2864), dim3(256), 0, stream,
                     h_w1, h_b1, h_wh, h_wo, g_w1, g_wh, wsH, wsG);

  hipLaunchKernelGGL(fused_nn, dim3(nwg), dim3(256), 0, stream,
                     x, h_bh, h_bo,
                     g_b1, g_bh, g_wo, g_bo,
                     (const __bf16*)wsH, (const __bf16*)wsG,
                     (float*)d_out, Btot, nwg);
}